// Round 1
// baseline (485.571 us; speedup 1.0000x reference)
//
#include <hip/hip_runtime.h>
#include <cstdint>

// Problem dims (hardcoded): B=8192, V=4, D=H=1024, C=10, M = B*V = 32768.
// Pipeline: cast/transposes -> qkv GEMM (bf16 MFMA) -> attn+LN -> FFN GEMM -> split-K classifier.

typedef __bf16 bf16x8_t __attribute__((ext_vector_type(8)));
typedef float f32x4_t __attribute__((ext_vector_type(4)));

__device__ __forceinline__ float b2f(unsigned short u) {
    union { unsigned int i; float f; } c; c.i = ((unsigned int)u) << 16; return c.f;
}
__device__ __forceinline__ unsigned short f2b(float f) {
    union { float f; unsigned int i; } c; c.f = f;
    unsigned int x = c.i;
    return (unsigned short)((x + 0x7fffu + ((x >> 16) & 1u)) >> 16);
}
__device__ __forceinline__ void gload16(void* g, void* l) {
    __builtin_amdgcn_global_load_lds((__attribute__((address_space(1))) void*)g,
                                     (__attribute__((address_space(3))) void*)l, 16, 0, 0);
}

// ---------------- cast f32 -> bf16 (vectorized) ----------------
__global__ __launch_bounds__(256) void cast_bf16(const float* __restrict__ in,
                                                 unsigned short* __restrict__ out, int n) {
    int stride = gridDim.x * blockDim.x * 8;
    for (int i = (blockIdx.x * blockDim.x + threadIdx.x) * 8; i < n; i += stride) {
        float4 a = *(const float4*)(in + i);
        float4 b = *(const float4*)(in + i + 4);
        ushort4 o1; o1.x = f2b(a.x); o1.y = f2b(a.y); o1.z = f2b(a.z); o1.w = f2b(a.w);
        ushort4 o2; o2.x = f2b(b.x); o2.y = f2b(b.y); o2.z = f2b(b.z); o2.w = f2b(b.w);
        *(ushort4*)(out + i) = o1;
        *(ushort4*)(out + i + 4) = o2;
    }
}

// ---------------- transpose + cast: W (1024x1024 f32, KxN) -> Wt (NxK bf16) ----------------
__global__ __launch_bounds__(256) void transpose_cast(const float* __restrict__ in,
                                                      unsigned short* __restrict__ outp) {
    __shared__ float tile[32][33];
    int k0 = blockIdx.y * 32, n0 = blockIdx.x * 32;
    int tx = threadIdx.x, ty = threadIdx.y; // 32 x 8
#pragma unroll
    for (int i = 0; i < 32; i += 8)
        tile[ty + i][tx] = in[(size_t)(k0 + ty + i) * 1024 + n0 + tx];
    __syncthreads();
#pragma unroll
    for (int i = 0; i < 32; i += 8)
        outp[(size_t)(n0 + ty + i) * 1024 + k0 + tx] = f2b(tile[tx][ty + i]);
}

// ---------------- Wf (4096x10 f32) -> Wft (16x4096 bf16, zero-padded) ----------------
__global__ __launch_bounds__(256) void wft_prep(const float* __restrict__ Wf,
                                                unsigned short* __restrict__ wft) {
    int tid = blockIdx.x * 256 + threadIdx.x; // 65536 total
    int n = tid >> 12, k = tid & 4095;
    wft[tid] = (n < 10) ? f2b(Wf[(size_t)k * 10 + n]) : (unsigned short)0;
}

// ---------------- main GEMM: C = A(M,K) @ Bt(N,K)^T (+bias)(+relu), bf16 in/out ----------------
// 128x128 tile, BK=64, 4 waves (2x2 of 64x64), mfma_f32_16x16x32_bf16.
// LDS rows are 128B (8 slots of 16B), XOR-swizzled: data slot s stored at position s^(row&7).
template<int RELU>
__global__ __launch_bounds__(256) void gemm_bt(
    const unsigned short* __restrict__ A, const unsigned short* __restrict__ Bt,
    unsigned short* __restrict__ C,
    const float* __restrict__ bias0, const float* __restrict__ bias1, const float* __restrict__ bias2,
    int N, int K) {
    __shared__ __align__(16) short ldsA[128 * 64];
    __shared__ __align__(16) short ldsB[128 * 64];
    const int t = threadIdx.x;
    const int w = t >> 6, lane = t & 63;
    const int row0 = blockIdx.y * 128, col0 = blockIdx.x * 128;
    const int rl = lane >> 3;            // row within 8-row staging chunk
    const int sl = (lane & 7) ^ rl;      // pre-swizzled global k-slot for this lane

    const unsigned short* gA[4];
    const unsigned short* gB[4];
#pragma unroll
    for (int i = 0; i < 4; ++i) {
        int r = (w * 4 + i) * 8 + rl;
        gA[i] = A + (size_t)(row0 + r) * K + sl * 8;
        gB[i] = Bt + (size_t)(col0 + r) * K + sl * 8;
    }

    f32x4_t acc[4][4] = {};
    const int hi = lane >> 4;
    const int l7 = lane & 7;
    const int rA = (w >> 1) * 64 + (lane & 15);
    const int rB = (w & 1) * 64 + (lane & 15);

    for (int kt = 0; kt < K; kt += 64) {
#pragma unroll
        for (int i = 0; i < 4; ++i) gload16((void*)(gA[i] + kt), ldsA + (w * 4 + i) * 512);
#pragma unroll
        for (int i = 0; i < 4; ++i) gload16((void*)(gB[i] + kt), ldsB + (w * 4 + i) * 512);
        __syncthreads();
#pragma unroll
        for (int kk = 0; kk < 2; ++kk) {
            const int s = ((kk * 4 + hi) ^ l7) * 8;
            bf16x8_t af[4], bfr[4];
#pragma unroll
            for (int m = 0; m < 4; ++m) af[m] = *(const bf16x8_t*)&ldsA[(rA + m * 16) * 64 + s];
#pragma unroll
            for (int n = 0; n < 4; ++n) bfr[n] = *(const bf16x8_t*)&ldsB[(rB + n * 16) * 64 + s];
#pragma unroll
            for (int m = 0; m < 4; ++m)
#pragma unroll
                for (int n = 0; n < 4; ++n)
                    acc[m][n] = __builtin_amdgcn_mfma_f32_16x16x32_bf16(af[m], bfr[n], acc[m][n], 0, 0, 0);
        }
        __syncthreads();
    }

    const int wr = w >> 1, wc = w & 1;
#pragma unroll
    for (int n = 0; n < 4; ++n) {
        int col = col0 + wc * 64 + n * 16 + (lane & 15);
        int sel = col >> 10;
        const float* bp = (sel == 0) ? bias0 : ((sel == 1) ? bias1 : bias2);
        float bias = bp[col & 1023];
#pragma unroll
        for (int m = 0; m < 4; ++m) {
#pragma unroll
            for (int j = 0; j < 4; ++j) {
                int row = row0 + wr * 64 + m * 16 + ((lane >> 4) << 2) + j;
                float v = acc[m][n][j] + bias;
                if (RELU) v = fmaxf(v, 0.0f);
                C[(size_t)row * N + col] = f2b(v);
            }
        }
    }
}

// ---------------- attention over V=4 + residual + LayerNorm over (V*H)=4096 ----------------
// one block (256 threads) per sample; thread t owns h = 4t..4t+3 for all 4 views.
__global__ __launch_bounds__(256) void attn_ln(
    const unsigned short* __restrict__ qkv, const float* __restrict__ xt,
    unsigned short* __restrict__ xln) {
    __shared__ float red[64];
    __shared__ float attn_s[16];
    __shared__ float mv2[2];
    const int b = blockIdx.x, t = threadIdx.x;
    const int lane = t & 63, wid = t >> 6;
    const int h0 = t * 4;
    const size_t base = (size_t)b * 4 * 3072;

    float q[4][4], k[4][4], vv[4][4];
#pragma unroll
    for (int v = 0; v < 4; ++v) {
        const unsigned short* p = qkv + base + (size_t)v * 3072 + h0;
        ushort4 uq = *(const ushort4*)(p);
        ushort4 uk = *(const ushort4*)(p + 1024);
        ushort4 uv = *(const ushort4*)(p + 2048);
        q[v][0] = b2f(uq.x); q[v][1] = b2f(uq.y); q[v][2] = b2f(uq.z); q[v][3] = b2f(uq.w);
        k[v][0] = b2f(uk.x); k[v][1] = b2f(uk.y); k[v][2] = b2f(uk.z); k[v][3] = b2f(uk.w);
        vv[v][0] = b2f(uv.x); vv[v][1] = b2f(uv.y); vv[v][2] = b2f(uv.z); vv[v][3] = b2f(uv.w);
    }
    // partial scores
    float s[4][4];
#pragma unroll
    for (int v = 0; v < 4; ++v)
#pragma unroll
        for (int wv = 0; wv < 4; ++wv) {
            float acc = 0.f;
#pragma unroll
            for (int j = 0; j < 4; ++j) acc += q[v][j] * k[wv][j];
            s[v][wv] = acc;
        }
    // block-reduce 16 values
#pragma unroll
    for (int v = 0; v < 4; ++v)
#pragma unroll
        for (int wv = 0; wv < 4; ++wv) {
            float x = s[v][wv];
#pragma unroll
            for (int off = 32; off; off >>= 1) x += __shfl_down(x, off);
            if (lane == 0) red[wid * 16 + v * 4 + wv] = x;
        }
    __syncthreads();
    if (t < 16) {
        float tot = (red[t] + red[16 + t] + red[32 + t] + red[48 + t]) * 0.03125f; // /sqrt(1024)
        red[t] = tot;
    }
    __syncthreads();
    if (t < 4) {
        float s0 = red[t * 4], s1 = red[t * 4 + 1], s2 = red[t * 4 + 2], s3 = red[t * 4 + 3];
        float mx = fmaxf(fmaxf(s0, s1), fmaxf(s2, s3));
        float e0 = __expf(s0 - mx), e1 = __expf(s1 - mx), e2 = __expf(s2 - mx), e3 = __expf(s3 - mx);
        float inv = 1.f / (e0 + e1 + e2 + e3);
        attn_s[t * 4 + 0] = e0 * inv; attn_s[t * 4 + 1] = e1 * inv;
        attn_s[t * 4 + 2] = e2 * inv; attn_s[t * 4 + 3] = e3 * inv;
    }
    __syncthreads();
    float a_[4][4];
#pragma unroll
    for (int v = 0; v < 4; ++v)
#pragma unroll
        for (int wv = 0; wv < 4; ++wv) a_[v][wv] = attn_s[v * 4 + wv];

    float x[4][4];
    float sum = 0.f, sumsq = 0.f;
#pragma unroll
    for (int v = 0; v < 4; ++v) {
        float4 xr = *(const float4*)(xt + (size_t)(b * 4 + v) * 1024 + h0);
        float xv[4] = {xr.x, xr.y, xr.z, xr.w};
#pragma unroll
        for (int j = 0; j < 4; ++j) {
            float val = a_[v][0] * vv[0][j] + a_[v][1] * vv[1][j] +
                        a_[v][2] * vv[2][j] + a_[v][3] * vv[3][j] + xv[j];
            x[v][j] = val;
            sum += val; sumsq += val * val;
        }
    }
#pragma unroll
    for (int off = 32; off; off >>= 1) {
        sum += __shfl_down(sum, off);
        sumsq += __shfl_down(sumsq, off);
    }
    __syncthreads(); // protect red[] reuse
    if (lane == 0) { red[wid] = sum; red[8 + wid] = sumsq; }
    __syncthreads();
    if (t == 0) {
        float sm = red[0] + red[1] + red[2] + red[3];
        float sq = red[8] + red[9] + red[10] + red[11];
        float mean = sm * (1.f / 4096.f);
        float var = sq * (1.f / 4096.f) - mean * mean;
        mv2[0] = mean; mv2[1] = rsqrtf(var + 1e-5f);
    }
    __syncthreads();
    float mean = mv2[0], rstd = mv2[1];
#pragma unroll
    for (int v = 0; v < 4; ++v) {
        ushort4 o;
        o.x = f2b((x[v][0] - mean) * rstd);
        o.y = f2b((x[v][1] - mean) * rstd);
        o.z = f2b((x[v][2] - mean) * rstd);
        o.w = f2b((x[v][3] - mean) * rstd);
        *(ushort4*)(xln + (size_t)(b * 4 + v) * 1024 + h0) = o;
    }
}

// ---------------- classifier: partial[split] = h(8192x4096) @ Wft(16x4096)^T over K/4 ----------------
__global__ __launch_bounds__(256) void final_mfma(
    const unsigned short* __restrict__ A, const unsigned short* __restrict__ Bt,
    float* __restrict__ part) {
    __shared__ __align__(16) short ldsA[128 * 64];
    __shared__ __align__(16) short ldsB[16 * 64];
    const int t = threadIdx.x;
    const int w = t >> 6, lane = t & 63;
    const int row0 = blockIdx.x * 128;
    const int split = blockIdx.y;
    const int kbase = split * 1024;
    const int rl = lane >> 3;
    const int sl = (lane & 7) ^ rl;

    const unsigned short* gA[4];
#pragma unroll
    for (int i = 0; i < 4; ++i) {
        int r = (w * 4 + i) * 8 + rl;
        gA[i] = A + (size_t)(row0 + r) * 4096 + kbase + sl * 8;
    }
    const unsigned short* gB = Bt; // valid only for w<2
    if (w < 2) gB = Bt + (size_t)(w * 8 + rl) * 4096 + kbase + sl * 8;

    f32x4_t acc[2] = {};
    const int hi = lane >> 4;
    const int l7 = lane & 7;

    for (int kt = 0; kt < 1024; kt += 64) {
#pragma unroll
        for (int i = 0; i < 4; ++i) gload16((void*)(gA[i] + kt), ldsA + (w * 4 + i) * 512);
        if (w < 2) gload16((void*)(gB + kt), ldsB + w * 512);
        __syncthreads();
#pragma unroll
        for (int kk = 0; kk < 2; ++kk) {
            const int s = ((kk * 4 + hi) ^ l7) * 8;
            bf16x8_t bfr = *(const bf16x8_t*)&ldsB[(lane & 15) * 64 + s];
#pragma unroll
            for (int m = 0; m < 2; ++m) {
                bf16x8_t af = *(const bf16x8_t*)&ldsA[(w * 32 + m * 16 + (lane & 15)) * 64 + s];
                acc[m] = __builtin_amdgcn_mfma_f32_16x16x32_bf16(af, bfr, acc[m], 0, 0, 0);
            }
        }
        __syncthreads();
    }
    const int col = lane & 15;
    if (col < 10) {
#pragma unroll
        for (int m = 0; m < 2; ++m)
#pragma unroll
            for (int j = 0; j < 4; ++j) {
                int row = row0 + w * 32 + m * 16 + ((lane >> 4) << 2) + j;
                part[(size_t)split * 81920 + (size_t)row * 10 + col] = acc[m][j];
            }
    }
}

__global__ __launch_bounds__(256) void reduce_out(const float* __restrict__ part,
                                                  const float* __restrict__ bias,
                                                  float* __restrict__ out) {
    int i = blockIdx.x * 256 + threadIdx.x; // 81920 total
    if (i < 81920) {
        int c = i - (i / 10) * 10;
        out[i] = part[i] + part[81920 + i] + part[2 * 81920 + i] + part[3 * 81920 + i] + bias[c];
    }
}

extern "C" void kernel_launch(void* const* d_in, const int* in_sizes, int n_in,
                              void* d_out, int out_size, void* d_ws, size_t ws_size,
                              hipStream_t stream) {
    const float* xt = (const float*)d_in[0];
    const float* Wq = (const float*)d_in[1];
    const float* bq = (const float*)d_in[2];
    const float* Wk = (const float*)d_in[3];
    const float* bk = (const float*)d_in[4];
    const float* Wv = (const float*)d_in[5];
    const float* bv = (const float*)d_in[6];
    const float* W1 = (const float*)d_in[7];
    const float* b1 = (const float*)d_in[8];
    const float* Wf = (const float*)d_in[9];
    const float* bff = (const float*)d_in[10];
    float* out = (float*)d_out;
    char* ws = (char*)d_ws;

    // workspace layout (bytes); peak ~265.5 MiB
    unsigned short* xb  = (unsigned short*)(ws + 0);          // 64 MiB (reused as xln)
    unsigned short* wt3 = (unsigned short*)(ws + 67108864);   // 6 MiB  (Wq|Wk|Wv transposed)
    unsigned short* w1t = (unsigned short*)(ws + 73400320);   // 2 MiB
    unsigned short* wft = (unsigned short*)(ws + 75497472);   // 128 KiB
    float* part         = (float*)(ws + 75628544);            // 1.25 MiB
    unsigned short* qkv = (unsigned short*)(ws + 77070336);   // 192 MiB (reused as h)
    unsigned short* xln = xb;
    unsigned short* hbuf = qkv;

    cast_bf16<<<2048, 256, 0, stream>>>(xt, xb, 32768 * 1024);
    dim3 tb(32, 8), tg(32, 32);
    transpose_cast<<<tg, tb, 0, stream>>>(Wq, wt3);
    transpose_cast<<<tg, tb, 0, stream>>>(Wk, wt3 + 1024 * 1024);
    transpose_cast<<<tg, tb, 0, stream>>>(Wv, wt3 + 2 * 1024 * 1024);
    transpose_cast<<<tg, tb, 0, stream>>>(W1, w1t);
    wft_prep<<<256, 256, 0, stream>>>(Wf, wft);

    // qkv = xb @ [Wq|Wk|Wv]^T : M=32768, N=3072, K=1024
    gemm_bt<0><<<dim3(24, 256), 256, 0, stream>>>(xb, wt3, qkv, bq, bk, bv, 3072, 1024);
    // attention + residual + LN
    attn_ln<<<8192, 256, 0, stream>>>(qkv, xt, xln);
    // h = relu(xln @ W1^T + b1) : N=1024
    gemm_bt<1><<<dim3(8, 256), 256, 0, stream>>>(xln, w1t, hbuf, b1, b1, b1, 1024, 1024);
    // classifier split-K
    final_mfma<<<dim3(64, 4), 256, 0, stream>>>(hbuf, wft, part);
    reduce_out<<<320, 256, 0, stream>>>(part, bff, out);
}

// Round 2
// 451.233 us; speedup vs baseline: 1.0761x; 1.0761x over previous
//
#include <hip/hip_runtime.h>
#include <cstdint>

// Problem dims (hardcoded): B=8192, V=4, D=H=1024, C=10, M = B*V = 32768.
// Pipeline: cast/transposes -> qkv GEMM (256^2 8-phase bf16 MFMA) -> attn+LN -> FFN GEMM -> split-K classifier.

typedef __bf16 bf16x8_t __attribute__((ext_vector_type(8)));
typedef float f32x4_t __attribute__((ext_vector_type(4)));

__device__ __forceinline__ float b2f(unsigned short u) {
    union { unsigned int i; float f; } c; c.i = ((unsigned int)u) << 16; return c.f;
}
__device__ __forceinline__ unsigned short f2b(float f) {
    union { float f; unsigned int i; } c; c.f = f;
    unsigned int x = c.i;
    return (unsigned short)((x + 0x7fffu + ((x >> 16) & 1u)) >> 16);
}
__device__ __forceinline__ void gload16(void* g, void* l) {
    __builtin_amdgcn_global_load_lds((__attribute__((address_space(1))) void*)g,
                                     (__attribute__((address_space(3))) void*)l, 16, 0, 0);
}

// ---------------- cast f32 -> bf16 (vectorized) ----------------
__global__ __launch_bounds__(256) void cast_bf16(const float* __restrict__ in,
                                                 unsigned short* __restrict__ out, int n) {
    int stride = gridDim.x * blockDim.x * 8;
    for (int i = (blockIdx.x * blockDim.x + threadIdx.x) * 8; i < n; i += stride) {
        float4 a = *(const float4*)(in + i);
        float4 b = *(const float4*)(in + i + 4);
        ushort4 o1; o1.x = f2b(a.x); o1.y = f2b(a.y); o1.z = f2b(a.z); o1.w = f2b(a.w);
        ushort4 o2; o2.x = f2b(b.x); o2.y = f2b(b.y); o2.z = f2b(b.z); o2.w = f2b(b.w);
        *(ushort4*)(out + i) = o1;
        *(ushort4*)(out + i + 4) = o2;
    }
}

// ---------------- transpose + cast: W (1024x1024 f32, KxN) -> Wt (NxK bf16) ----------------
__global__ __launch_bounds__(256) void transpose_cast(const float* __restrict__ in,
                                                      unsigned short* __restrict__ outp) {
    __shared__ float tile[32][33];
    int k0 = blockIdx.y * 32, n0 = blockIdx.x * 32;
    int tx = threadIdx.x, ty = threadIdx.y; // 32 x 8
#pragma unroll
    for (int i = 0; i < 32; i += 8)
        tile[ty + i][tx] = in[(size_t)(k0 + ty + i) * 1024 + n0 + tx];
    __syncthreads();
#pragma unroll
    for (int i = 0; i < 32; i += 8)
        outp[(size_t)(n0 + ty + i) * 1024 + k0 + tx] = f2b(tile[tx][ty + i]);
}

// ---------------- Wf (4096x10 f32) -> Wft (16x4096 bf16, zero-padded) ----------------
__global__ __launch_bounds__(256) void wft_prep(const float* __restrict__ Wf,
                                                unsigned short* __restrict__ wft) {
    int tid = blockIdx.x * 256 + threadIdx.x; // 65536 total
    int n = tid >> 12, k = tid & 4095;
    wft[tid] = (n < 10) ? f2b(Wf[(size_t)k * 10 + n]) : (unsigned short)0;
}

// ---------------- 256x256 8-phase GEMM: C = A(M,K) @ Bt(N,K)^T (+bias)(+relu) ----------------
// 512 threads = 8 waves (2 Mx 4 N), per-wave C block 128x64 (8x4 16x16 frags).
// BK=64, LDS 128 KiB double-buffered, counted vmcnt(4) (T3+T4), setprio (T5),
// XOR swizzle slot^=(row&7) applied on pre-swizzled global src + ds_read (T2),
// bijective XCD swizzle on flattened grid (T1).
#define BAR() __builtin_amdgcn_s_barrier()
#define PRIO1() __builtin_amdgcn_s_setprio(1)
#define PRIO0() __builtin_amdgcn_s_setprio(0)
#define STAGE_A(H, L, KOFS, NB) \
    gload16((void*)(gAs + (size_t)((H)*128 + (L)*64) * KDIM + (KOFS)), \
            (void*)&ldsA[NB][(H)*8192 + (L)*4096 + ldst])
#define STAGE_B(H, L, KOFS, NB) \
    gload16((void*)(gBs + (size_t)((H)*128 + (L)*64) * KDIM + (KOFS)), \
            (void*)&ldsB[NB][(H)*8192 + (L)*4096 + ldst])
#define LDA8(AF, BA, MH) do { _Pragma("unroll") for (int m_ = 0; m_ < 4; ++m_) { \
    const int row_ = rA + (MH)*64 + m_*16; \
    AF[m_][0] = *(const bf16x8_t*)&BA[row_*64 + sk0]; \
    AF[m_][1] = *(const bf16x8_t*)&BA[row_*64 + sk1]; } } while (0)
#define LDB4(BF, BB, NH) do { _Pragma("unroll") for (int n_ = 0; n_ < 2; ++n_) { \
    const int row_ = rB + (NH)*32 + n_*16; \
    BF[n_][0] = *(const bf16x8_t*)&BB[row_*64 + sk0]; \
    BF[n_][1] = *(const bf16x8_t*)&BB[row_*64 + sk1]; } } while (0)
#define MM16(AF, BF, MB, NB) do { \
    _Pragma("unroll") for (int kh_ = 0; kh_ < 2; ++kh_) \
    _Pragma("unroll") for (int m_ = 0; m_ < 4; ++m_) \
    _Pragma("unroll") for (int n_ = 0; n_ < 2; ++n_) \
        acc[(MB)+m_][(NB)+n_] = __builtin_amdgcn_mfma_f32_16x16x32_bf16( \
            AF[m_][kh_], BF[n_][kh_], acc[(MB)+m_][(NB)+n_], 0, 0, 0); } while (0)

template<int RELU, int KDIM>
__global__ __launch_bounds__(512, 2) void gemm256(
    const unsigned short* __restrict__ A, const unsigned short* __restrict__ Bt,
    unsigned short* __restrict__ C,
    const float* __restrict__ bias0, const float* __restrict__ bias1, const float* __restrict__ bias2,
    int N) {
    constexpr int NT = KDIM / 64;
    __shared__ __align__(16) short ldsA[2][16384];
    __shared__ __align__(16) short ldsB[2][16384];

    // bijective XCD swizzle (grid % 8 == 0 at both call sites)
    const int nwg = gridDim.x;
    const int wg = blockIdx.x;
    const int swz = (wg & 7) * (nwg >> 3) + (wg >> 3);
    const int nxb = N >> 8;
    const int bx = swz % nxb, by = swz / nxb;
    const int row0 = by * 256, col0 = bx * 256;

    const int tid = threadIdx.x;
    const int w = tid >> 6, lane = tid & 63;
    const int wr = w >> 2, wc = w & 3;      // 2 x 4 waves
    const int hi = lane >> 4, l7 = lane & 7;

    // staging maps (pre-swizzled global source, linear LDS dest)
    const int srow = tid >> 3;                                  // 0..63
    const int sslot8 = ((tid & 7) ^ (srow & 7)) * 8;
    const unsigned short* gAs = A + (size_t)(row0 + srow) * KDIM + sslot8;
    const unsigned short* gBs = Bt + (size_t)(col0 + srow) * KDIM + sslot8;
    const int ldst = tid * 8;

    // ds_read fragment maps
    const int rA = wr * 128 + (lane & 15);
    const int rB = wc * 64 + (lane & 15);
    const int sk0 = (hi ^ l7) * 8;
    const int sk1 = ((4 + hi) ^ l7) * 8;

    f32x4_t acc[8][4] = {};
    bf16x8_t af[4][2], bf0[2][2], bf1[2][2];

    // prologue: tile0 (buf0) fully + tile1 A-halves (buf1)
    STAGE_A(0, 0, 0, 0); STAGE_A(0, 1, 0, 0); STAGE_A(1, 0, 0, 0); STAGE_A(1, 1, 0, 0);
    STAGE_B(0, 0, 0, 0); STAGE_B(0, 1, 0, 0); STAGE_B(1, 0, 0, 0); STAGE_B(1, 1, 0, 0);
    STAGE_A(0, 0, 64, 1); STAGE_A(0, 1, 64, 1); STAGE_A(1, 0, 64, 1); STAGE_A(1, 1, 64, 1);
    asm volatile("s_waitcnt vmcnt(4)" ::: "memory");
    BAR();

#pragma unroll 2
    for (int t = 0; t < NT; ++t) {
        const int cur = t & 1, nxt = cur ^ 1;
        const short* bA = ldsA[cur];
        const short* bB = ldsB[cur];
        const int kt = t * 64;
        const bool sB = (t <= NT - 2);   // stage B-halves of tile t+1 -> buf[nxt]
        const bool sA2 = (t <= NT - 3);  // stage A-halves of tile t+2 -> buf[cur]
        // P0
        LDA8(af, bA, 0);
        LDB4(bf0, bB, 0);
        if (sB) { STAGE_B(0, 0, kt + 64, nxt); STAGE_B(0, 1, kt + 64, nxt); }
        BAR(); PRIO1(); MM16(af, bf0, 0, 0); PRIO0(); BAR();
        // P1
        LDB4(bf1, bB, 1);
        if (sB) { STAGE_B(1, 0, kt + 64, nxt); STAGE_B(1, 1, kt + 64, nxt); }
        BAR(); PRIO1(); MM16(af, bf1, 0, 2); PRIO0(); BAR();
        // P2
        LDA8(af, bA, 1);
        if (sA2) { STAGE_A(0, 0, kt + 128, cur); STAGE_A(0, 1, kt + 128, cur); }
        BAR(); PRIO1(); MM16(af, bf1, 4, 2); PRIO0(); BAR();
        // P3
        LDB4(bf0, bB, 0);
        if (sA2) {
            STAGE_A(1, 0, kt + 128, cur); STAGE_A(1, 1, kt + 128, cur);
            asm volatile("s_waitcnt vmcnt(4)" ::: "memory");
        } else if (sB) {
            asm volatile("s_waitcnt vmcnt(0)" ::: "memory");
        }
        BAR(); PRIO1(); MM16(af, bf0, 4, 0); PRIO0(); BAR();
    }

    // epilogue
    const int wrow = row0 + wr * 128;
    const int wcol = col0 + wc * 64;
#pragma unroll
    for (int nf = 0; nf < 4; ++nf) {
        const int col = wcol + nf * 16 + (lane & 15);
        const int sel = col >> 10;
        const float* bp = (sel == 0) ? bias0 : ((sel == 1) ? bias1 : bias2);
        const float bias = bp[col & 1023];
#pragma unroll
        for (int mf = 0; mf < 8; ++mf) {
#pragma unroll
            for (int j = 0; j < 4; ++j) {
                const int row = wrow + mf * 16 + hi * 4 + j;
                float v = acc[mf][nf][j] + bias;
                if (RELU) v = fmaxf(v, 0.0f);
                C[(size_t)row * N + col] = f2b(v);
            }
        }
    }
}
#undef BAR
#undef PRIO1
#undef PRIO0
#undef STAGE_A
#undef STAGE_B
#undef LDA8
#undef LDB4
#undef MM16

// ---------------- attention over V=4 + residual + LayerNorm over (V*H)=4096 ----------------
// one block (256 threads) per sample; thread t owns h = 4t..4t+3 for all 4 views.
__global__ __launch_bounds__(256) void attn_ln(
    const unsigned short* __restrict__ qkv, const unsigned short* __restrict__ xb,
    unsigned short* __restrict__ xln) {
    __shared__ float red[64];
    __shared__ float attn_s[16];
    __shared__ float mv2[2];
    const int b = blockIdx.x, t = threadIdx.x;
    const int lane = t & 63, wid = t >> 6;
    const int h0 = t * 4;
    const size_t base = (size_t)b * 4 * 3072;

    float q[4][4], k[4][4], vv[4][4];
#pragma unroll
    for (int v = 0; v < 4; ++v) {
        const unsigned short* p = qkv + base + (size_t)v * 3072 + h0;
        ushort4 uq = *(const ushort4*)(p);
        ushort4 uk = *(const ushort4*)(p + 1024);
        ushort4 uv = *(const ushort4*)(p + 2048);
        q[v][0] = b2f(uq.x); q[v][1] = b2f(uq.y); q[v][2] = b2f(uq.z); q[v][3] = b2f(uq.w);
        k[v][0] = b2f(uk.x); k[v][1] = b2f(uk.y); k[v][2] = b2f(uk.z); k[v][3] = b2f(uk.w);
        vv[v][0] = b2f(uv.x); vv[v][1] = b2f(uv.y); vv[v][2] = b2f(uv.z); vv[v][3] = b2f(uv.w);
    }
    float s[4][4];
#pragma unroll
    for (int v = 0; v < 4; ++v)
#pragma unroll
        for (int wv = 0; wv < 4; ++wv) {
            float acc = 0.f;
#pragma unroll
            for (int j = 0; j < 4; ++j) acc += q[v][j] * k[wv][j];
            s[v][wv] = acc;
        }
#pragma unroll
    for (int v = 0; v < 4; ++v)
#pragma unroll
        for (int wv = 0; wv < 4; ++wv) {
            float x = s[v][wv];
#pragma unroll
            for (int off = 32; off; off >>= 1) x += __shfl_down(x, off);
            if (lane == 0) red[wid * 16 + v * 4 + wv] = x;
        }
    __syncthreads();
    if (t < 16) {
        float tot = (red[t] + red[16 + t] + red[32 + t] + red[48 + t]) * 0.03125f; // /sqrt(1024)
        red[t] = tot;
    }
    __syncthreads();
    if (t < 4) {
        float s0 = red[t * 4], s1 = red[t * 4 + 1], s2 = red[t * 4 + 2], s3 = red[t * 4 + 3];
        float mx = fmaxf(fmaxf(s0, s1), fmaxf(s2, s3));
        float e0 = __expf(s0 - mx), e1 = __expf(s1 - mx), e2 = __expf(s2 - mx), e3 = __expf(s3 - mx);
        float inv = 1.f / (e0 + e1 + e2 + e3);
        attn_s[t * 4 + 0] = e0 * inv; attn_s[t * 4 + 1] = e1 * inv;
        attn_s[t * 4 + 2] = e2 * inv; attn_s[t * 4 + 3] = e3 * inv;
    }
    __syncthreads();
    float a_[4][4];
#pragma unroll
    for (int v = 0; v < 4; ++v)
#pragma unroll
        for (int wv = 0; wv < 4; ++wv) a_[v][wv] = attn_s[v * 4 + wv];

    float x[4][4];
    float sum = 0.f, sumsq = 0.f;
#pragma unroll
    for (int v = 0; v < 4; ++v) {
        ushort4 xr = *(const ushort4*)(xb + (size_t)(b * 4 + v) * 1024 + h0);
        float xv[4] = {b2f(xr.x), b2f(xr.y), b2f(xr.z), b2f(xr.w)};
#pragma unroll
        for (int j = 0; j < 4; ++j) {
            float val = a_[v][0] * vv[0][j] + a_[v][1] * vv[1][j] +
                        a_[v][2] * vv[2][j] + a_[v][3] * vv[3][j] + xv[j];
            x[v][j] = val;
            sum += val; sumsq += val * val;
        }
    }
#pragma unroll
    for (int off = 32; off; off >>= 1) {
        sum += __shfl_down(sum, off);
        sumsq += __shfl_down(sumsq, off);
    }
    __syncthreads(); // protect red[] reuse
    if (lane == 0) { red[wid] = sum; red[8 + wid] = sumsq; }
    __syncthreads();
    if (t == 0) {
        float sm = red[0] + red[1] + red[2] + red[3];
        float sq = red[8] + red[9] + red[10] + red[11];
        float mean = sm * (1.f / 4096.f);
        float var = sq * (1.f / 4096.f) - mean * mean;
        mv2[0] = mean; mv2[1] = rsqrtf(var + 1e-5f);
    }
    __syncthreads();
    float mean = mv2[0], rstd = mv2[1];
#pragma unroll
    for (int v = 0; v < 4; ++v) {
        ushort4 o;
        o.x = f2b((x[v][0] - mean) * rstd);
        o.y = f2b((x[v][1] - mean) * rstd);
        o.z = f2b((x[v][2] - mean) * rstd);
        o.w = f2b((x[v][3] - mean) * rstd);
        *(ushort4*)(xln + (size_t)(b * 4 + v) * 1024 + h0) = o;
    }
}

// ---------------- classifier: partial[split] = h(8192x4096) @ Wft(16x4096)^T over K/4 ----------------
__global__ __launch_bounds__(256) void final_mfma(
    const unsigned short* __restrict__ A, const unsigned short* __restrict__ Bt,
    float* __restrict__ part) {
    __shared__ __align__(16) short ldsA[128 * 64];
    __shared__ __align__(16) short ldsB[16 * 64];
    const int t = threadIdx.x;
    const int w = t >> 6, lane = t & 63;
    const int row0 = blockIdx.x * 128;
    const int split = blockIdx.y;
    const int kbase = split * 1024;
    const int rl = lane >> 3;
    const int sl = (lane & 7) ^ rl;

    const unsigned short* gA[4];
#pragma unroll
    for (int i = 0; i < 4; ++i) {
        int r = (w * 4 + i) * 8 + rl;
        gA[i] = A + (size_t)(row0 + r) * 4096 + kbase + sl * 8;
    }
    const unsigned short* gB = Bt;
    if (w < 2) gB = Bt + (size_t)(w * 8 + rl) * 4096 + kbase + sl * 8;

    f32x4_t acc[2] = {};
    const int hi = lane >> 4;
    const int l7 = lane & 7;

    for (int kt = 0; kt < 1024; kt += 64) {
#pragma unroll
        for (int i = 0; i < 4; ++i) gload16((void*)(gA[i] + kt), ldsA + (w * 4 + i) * 512);
        if (w < 2) gload16((void*)(gB + kt), ldsB + w * 512);
        __syncthreads();
#pragma unroll
        for (int kk = 0; kk < 2; ++kk) {
            const int s = ((kk * 4 + hi) ^ l7) * 8;
            bf16x8_t bfr = *(const bf16x8_t*)&ldsB[(lane & 15) * 64 + s];
#pragma unroll
            for (int m = 0; m < 2; ++m) {
                bf16x8_t af = *(const bf16x8_t*)&ldsA[(w * 32 + m * 16 + (lane & 15)) * 64 + s];
                acc[m] = __builtin_amdgcn_mfma_f32_16x16x32_bf16(af, bfr, acc[m], 0, 0, 0);
            }
        }
        __syncthreads();
    }
    const int col = lane & 15;
    if (col < 10) {
#pragma unroll
        for (int m = 0; m < 2; ++m)
#pragma unroll
            for (int j = 0; j < 4; ++j) {
                int row = row0 + w * 32 + m * 16 + ((lane >> 4) << 2) + j;
                part[(size_t)split * 81920 + (size_t)row * 10 + col] = acc[m][j];
            }
    }
}

__global__ __launch_bounds__(256) void reduce_out(const float* __restrict__ part,
                                                  const float* __restrict__ bias,
                                                  float* __restrict__ out) {
    int i = blockIdx.x * 256 + threadIdx.x; // 81920 total
    if (i < 81920) {
        int c = i - (i / 10) * 10;
        out[i] = part[i] + part[81920 + i] + part[2 * 81920 + i] + part[3 * 81920 + i] + bias[c];
    }
}

extern "C" void kernel_launch(void* const* d_in, const int* in_sizes, int n_in,
                              void* d_out, int out_size, void* d_ws, size_t ws_size,
                              hipStream_t stream) {
    const float* xt = (const float*)d_in[0];
    const float* Wq = (const float*)d_in[1];
    const float* bq = (const float*)d_in[2];
    const float* Wk = (const float*)d_in[3];
    const float* bk = (const float*)d_in[4];
    const float* Wv = (const float*)d_in[5];
    const float* bv = (const float*)d_in[6];
    const float* W1 = (const float*)d_in[7];
    const float* b1 = (const float*)d_in[8];
    const float* Wf = (const float*)d_in[9];
    const float* bff = (const float*)d_in[10];
    float* out = (float*)d_out;
    char* ws = (char*)d_ws;

    // workspace layout (bytes); peak ~265.5 MiB
    unsigned short* xb  = (unsigned short*)(ws + 0);          // 64 MiB (reused as xln)
    unsigned short* wt3 = (unsigned short*)(ws + 67108864);   // 6 MiB  (Wq|Wk|Wv transposed)
    unsigned short* w1t = (unsigned short*)(ws + 73400320);   // 2 MiB
    unsigned short* wft = (unsigned short*)(ws + 75497472);   // 128 KiB
    float* part         = (float*)(ws + 75628544);            // 1.25 MiB
    unsigned short* qkv = (unsigned short*)(ws + 77070336);   // 192 MiB (reused as h)
    unsigned short* xln = xb;
    unsigned short* hbuf = qkv;

    cast_bf16<<<2048, 256, 0, stream>>>(xt, xb, 32768 * 1024);
    dim3 tb(32, 8), tg(32, 32);
    transpose_cast<<<tg, tb, 0, stream>>>(Wq, wt3);
    transpose_cast<<<tg, tb, 0, stream>>>(Wk, wt3 + 1024 * 1024);
    transpose_cast<<<tg, tb, 0, stream>>>(Wv, wt3 + 2 * 1024 * 1024);
    transpose_cast<<<tg, tb, 0, stream>>>(W1, w1t);
    wft_prep<<<256, 256, 0, stream>>>(Wf, wft);

    // qkv = xb @ [Wq|Wk|Wv]^T : M=32768, N=3072, K=1024 -> grid 12*128 = 1536 (%8==0)
    gemm256<0, 1024><<<1536, 512, 0, stream>>>(xb, wt3, qkv, bq, bk, bv, 3072);
    // attention + residual + LN
    attn_ln<<<8192, 256, 0, stream>>>(qkv, xb, xln);
    // h = relu(xln @ W1^T + b1) : N=1024 -> grid 4*128 = 512 (%8==0)
    gemm256<1, 1024><<<512, 512, 0, stream>>>(xln, w1t, hbuf, b1, b1, b1, 1024);
    // classifier split-K
    final_mfma<<<dim3(64, 4), 256, 0, stream>>>(hbuf, wft, part);
    reduce_out<<<320, 256, 0, stream>>>(part, bff, out);
}

// Round 3
// 385.303 us; speedup vs baseline: 1.2602x; 1.1711x over previous
//
#include <hip/hip_runtime.h>
#include <cstdint>

// Problem dims (hardcoded): B=8192, V=4, D=H=1024, C=10, M = B*V = 32768.
// Pipeline: cast/transposes -> qkv GEMM (256^2, 4-phase/K-tile, 1-barrier phases) -> attn+LN -> FFN GEMM -> split-K classifier.

typedef __bf16 bf16x8_t __attribute__((ext_vector_type(8)));
typedef float f32x4_t __attribute__((ext_vector_type(4)));
typedef unsigned short ushort8_t __attribute__((ext_vector_type(8)));

__device__ __forceinline__ float b2f(unsigned short u) {
    union { unsigned int i; float f; } c; c.i = ((unsigned int)u) << 16; return c.f;
}
__device__ __forceinline__ unsigned short f2b(float f) {
    union { float f; unsigned int i; } c; c.f = f;
    unsigned int x = c.i;
    return (unsigned short)((x + 0x7fffu + ((x >> 16) & 1u)) >> 16);
}
__device__ __forceinline__ void gload16(const void* g, void* l) {
    __builtin_amdgcn_global_load_lds((const __attribute__((address_space(1))) void*)g,
                                     (__attribute__((address_space(3))) void*)l, 16, 0, 0);
}

// ---------------- cast f32 -> bf16 (vectorized) ----------------
__global__ __launch_bounds__(256) void cast_bf16(const float* __restrict__ in,
                                                 unsigned short* __restrict__ out, int n) {
    int stride = gridDim.x * blockDim.x * 8;
    for (int i = (blockIdx.x * blockDim.x + threadIdx.x) * 8; i < n; i += stride) {
        float4 a = *(const float4*)(in + i);
        float4 b = *(const float4*)(in + i + 4);
        ushort4 o1; o1.x = f2b(a.x); o1.y = f2b(a.y); o1.z = f2b(a.z); o1.w = f2b(a.w);
        ushort4 o2; o2.x = f2b(b.x); o2.y = f2b(b.y); o2.z = f2b(b.z); o2.w = f2b(b.w);
        *(ushort4*)(out + i) = o1;
        *(ushort4*)(out + i + 4) = o2;
    }
}

// ---------------- transpose + cast: W (1024x1024 f32, KxN) -> Wt (NxK bf16) ----------------
__global__ __launch_bounds__(256) void transpose_cast(const float* __restrict__ in,
                                                      unsigned short* __restrict__ outp) {
    __shared__ float tile[32][33];
    int k0 = blockIdx.y * 32, n0 = blockIdx.x * 32;
    int tx = threadIdx.x, ty = threadIdx.y; // 32 x 8
#pragma unroll
    for (int i = 0; i < 32; i += 8)
        tile[ty + i][tx] = in[(size_t)(k0 + ty + i) * 1024 + n0 + tx];
    __syncthreads();
#pragma unroll
    for (int i = 0; i < 32; i += 8)
        outp[(size_t)(n0 + ty + i) * 1024 + k0 + tx] = f2b(tile[tx][ty + i]);
}

// ---------------- Wf (4096x10 f32) -> Wft (16x4096 bf16, zero-padded) ----------------
__global__ __launch_bounds__(256) void wft_prep(const float* __restrict__ Wf,
                                                unsigned short* __restrict__ wft) {
    int tid = blockIdx.x * 256 + threadIdx.x; // 65536 total
    int n = tid >> 12, k = tid & 4095;
    wft[tid] = (n < 10) ? f2b(Wf[(size_t)k * 10 + n]) : (unsigned short)0;
}

// ---------------- 256x256 GEMM: C = A(M,K) @ Bt(N,K)^T (+bias)(+relu) ----------------
// 8 waves (wr in {0,1}: M rows wr*64 interleaved by half; wc in {0..3}: N cols wc*32 by half).
// 4 separate 32KB LDS arrays (AA-provably disjoint) double-buffer A/B tiles.
// Per K-tile: 4 phases, ONE raw barrier each, 2 counted vmcnt(2) waits; prefetch = next tile
// into the other buffer (race-free: its readers finished >=2 barriers earlier).
#define BAR() __builtin_amdgcn_s_barrier()
#define PRIO1() __builtin_amdgcn_s_setprio(1)
#define PRIO0() __builtin_amdgcn_s_setprio(0)
#define VMC(N) asm volatile("s_waitcnt vmcnt(" #N ")" ::: "memory")

#define STGA(ARR, H, L, KOFS) \
    gload16((const void*)(gAs + (size_t)((H)*128 + (L)*64) * KDIM + (KOFS)), \
            (void*)&ARR[(H)*8192 + (L)*4096 + tid8])
#define STGB(ARR, H, L, KOFS) \
    gload16((const void*)(gBs + (size_t)((H)*128 + (L)*64) * KDIM + (KOFS)), \
            (void*)&ARR[(H)*8192 + (L)*4096 + tid8])
#define LDA(AF, ARR, MH) do { _Pragma("unroll") for (int m_ = 0; m_ < 4; ++m_) { \
    const int row_ = (MH)*128 + rAbase + m_*16; \
    AF[m_][0] = *(const bf16x8_t*)&ARR[row_*64 + sk0]; \
    AF[m_][1] = *(const bf16x8_t*)&ARR[row_*64 + sk1]; } } while (0)
#define LDB(BF, ARR, NH) do { _Pragma("unroll") for (int n_ = 0; n_ < 2; ++n_) { \
    const int row_ = (NH)*128 + rBbase + n_*16; \
    BF[n_][0] = *(const bf16x8_t*)&ARR[row_*64 + sk0]; \
    BF[n_][1] = *(const bf16x8_t*)&ARR[row_*64 + sk1]; } } while (0)
#define MM16(AF, BF, MB, NB) do { \
    _Pragma("unroll") for (int kh_ = 0; kh_ < 2; ++kh_) \
    _Pragma("unroll") for (int m_ = 0; m_ < 4; ++m_) \
    _Pragma("unroll") for (int n_ = 0; n_ < 2; ++n_) \
        acc[(MB)+m_][(NB)+n_] = __builtin_amdgcn_mfma_f32_16x16x32_bf16( \
            AF[m_][kh_], BF[n_][kh_], acc[(MB)+m_][(NB)+n_], 0, 0, 0); } while (0)

// one K-tile: read (AR,BR), stage tile T+1 -> (AW,BW)
#define KBODY(T, AR, BR, AW, BW) do { \
    const int kn_ = ((T) + 1) * 64; \
    const bool st_ = (T) < NT - 1; \
    /* P0 */ \
    LDA(af, AR, 0); \
    LDB(bf0, BR, 0); \
    if (st_) { STGA(AW, 0, 0, kn_); STGA(AW, 0, 1, kn_); } \
    PRIO1(); MM16(af, bf0, 0, 0); PRIO0(); \
    if (st_) { VMC(2); } else { VMC(0); } \
    BAR(); \
    /* P1 */ \
    LDB(bf1, BR, 1); \
    if (st_) { STGA(AW, 1, 0, kn_); STGA(AW, 1, 1, kn_); } \
    PRIO1(); MM16(af, bf1, 0, 2); PRIO0(); \
    BAR(); \
    /* P2 */ \
    LDA(af, AR, 1); \
    if (st_) { STGB(BW, 0, 0, kn_); STGB(BW, 0, 1, kn_); } \
    PRIO1(); MM16(af, bf1, 4, 2); PRIO0(); \
    BAR(); \
    /* P3 */ \
    if (st_) { STGB(BW, 1, 0, kn_); STGB(BW, 1, 1, kn_); } \
    PRIO1(); MM16(af, bf0, 4, 0); PRIO0(); \
    VMC(2); \
    BAR(); \
} while (0)

template<int RELU, int KDIM>
__global__ __launch_bounds__(512, 2) void gemm256(
    const unsigned short* __restrict__ A, const unsigned short* __restrict__ Bt,
    unsigned short* __restrict__ C,
    const float* __restrict__ bias0, const float* __restrict__ bias1, const float* __restrict__ bias2,
    int N) {
    constexpr int NT = KDIM / 64;
    __shared__ __align__(16) short As0[16384];
    __shared__ __align__(16) short As1[16384];
    __shared__ __align__(16) short Bs0[16384];
    __shared__ __align__(16) short Bs1[16384];

    // bijective XCD swizzle (grid % 8 == 0 at both call sites)
    const int nwg = gridDim.x;
    const int wg = blockIdx.x;
    const int swz = (wg & 7) * (nwg >> 3) + (wg >> 3);
    const int nxb = N >> 8;
    const int bx = swz % nxb, by = swz / nxb;
    const int row0 = by * 256, col0 = bx * 256;

    const int tid = threadIdx.x;
    const int w = tid >> 6, lane = tid & 63;
    const int wr = w >> 2, wc = w & 3;          // 2 x 4 waves
    const int hi = lane >> 4, l7 = lane & 7, l15 = lane & 15;

    // staging maps (pre-swizzled global source, linear LDS dest)
    const int srow = tid >> 3;                               // 0..63
    const int sslot8 = ((tid & 7) ^ (srow & 7)) * 8;
    const unsigned short* gAs = A + (size_t)(row0 + srow) * KDIM + sslot8;
    const unsigned short* gBs = Bt + (size_t)(col0 + srow) * KDIM + sslot8;
    const int tid8 = tid * 8;

    // ds_read fragment maps
    const int rAbase = wr * 64 + l15;    // + MH*128 + m*16
    const int rBbase = wc * 32 + l15;    // + NH*128 + n*16
    const int sk0 = (hi ^ l7) * 8;
    const int sk1 = ((4 + hi) ^ l7) * 8;

    f32x4_t acc[8][4] = {};
    bf16x8_t af[4][2], bf0[2][2], bf1[2][2];

    // prologue: tile0 -> As0/Bs0 (issue order AH0,AH1,BH0,BH1)
    STGA(As0, 0, 0, 0); STGA(As0, 0, 1, 0);
    STGA(As0, 1, 0, 0); STGA(As0, 1, 1, 0);
    STGB(Bs0, 0, 0, 0); STGB(Bs0, 0, 1, 0);
    STGB(Bs0, 1, 0, 0); STGB(Bs0, 1, 1, 0);
    VMC(2);   // AH0,AH1,BH0 landed; BH1 stays in flight (drained at end-P0)
    BAR();

    for (int t2 = 0; t2 < NT; t2 += 2) {
        KBODY(t2,     As0, Bs0, As1, Bs1);
        KBODY(t2 + 1, As1, Bs1, As0, Bs0);
    }

    // ---------- epilogue: stage C-tile in LDS (swizzled), write coalesced ----------
    // C rows 0-63 -> As0, 64-127 -> As1, 128-191 -> Bs0, 192-255 -> Bs1.
    float biasv[4];
#pragma unroll
    for (int nh = 0; nh < 2; ++nh)
#pragma unroll
        for (int nf = 0; nf < 2; ++nf) {
            const int col = col0 + nh * 128 + wc * 32 + nf * 16 + l15;
            const int sel = col >> 10;
            const float* bp = (sel == 0) ? bias0 : ((sel == 1) ? bias1 : bias2);
            biasv[nh * 2 + nf] = bp[col & 1023];
        }
#pragma unroll
    for (int mh = 0; mh < 2; ++mh) {
        short* arr0 = (mh == 0) ? (wr ? As1 : As0) : (wr ? Bs1 : Bs0);
#pragma unroll
        for (int mf = 0; mf < 4; ++mf)
#pragma unroll
            for (int j = 0; j < 4; ++j) {
                const int row = mh * 128 + wr * 64 + mf * 16 + hi * 4 + j;
                const int lr = row & 63;
                const int s_ = (row >> 2) & 3;
#pragma unroll
                for (int nh = 0; nh < 2; ++nh)
#pragma unroll
                    for (int nf = 0; nf < 2; ++nf) {
                        const int dc = nh * 128 + wc * 32 + nf * 16 + l15;
                        const int sidx = lr * 256 + (((dc >> 4) ^ s_) << 4) + (dc & 15);
                        float v = acc[mh * 4 + mf][nh * 2 + nf][j] + biasv[nh * 2 + nf];
                        if (RELU) v = fmaxf(v, 0.0f);
                        arr0[sidx] = (short)f2b(v);
                    }
            }
    }
    __syncthreads();
#pragma unroll
    for (int it = 0; it < 16; ++it) {
        const int gb = it * 8192 + tid * 16;           // byte offset within 256x256x2B tile
        const int r = gb >> 9;                          // row 0..255
        const int lr = r & 63;
        const short* arr = (r < 64) ? As0 : ((r < 128) ? As1 : ((r < 192) ? Bs0 : Bs1));
        const int g = (gb >> 5) & 15;
        const int sidx = lr * 256 + ((g ^ ((r >> 2) & 3)) << 4) + ((gb >> 1) & 7) * 0 + ((gb & 31) >> 1);
        ushort8_t vvv = *(const ushort8_t*)&arr[sidx];
        const int col = (gb & 511) >> 1;
        *(ushort8_t*)&C[(size_t)(row0 + r) * N + col0 + col] = vvv;
    }
}
#undef BAR
#undef PRIO1
#undef PRIO0
#undef VMC
#undef STGA
#undef STGB
#undef LDA
#undef LDB
#undef MM16
#undef KBODY

// ---------------- attention over V=4 + residual + LayerNorm over (V*H)=4096 ----------------
__global__ __launch_bounds__(256) void attn_ln(
    const unsigned short* __restrict__ qkv, const unsigned short* __restrict__ xb,
    unsigned short* __restrict__ xln) {
    __shared__ float red[64];
    __shared__ float attn_s[16];
    __shared__ float mv2[2];
    const int b = blockIdx.x, t = threadIdx.x;
    const int lane = t & 63, wid = t >> 6;
    const int h0 = t * 4;
    const size_t base = (size_t)b * 4 * 3072;

    float q[4][4], k[4][4], vv[4][4];
#pragma unroll
    for (int v = 0; v < 4; ++v) {
        const unsigned short* p = qkv + base + (size_t)v * 3072 + h0;
        ushort4 uq = *(const ushort4*)(p);
        ushort4 uk = *(const ushort4*)(p + 1024);
        ushort4 uv = *(const ushort4*)(p + 2048);
        q[v][0] = b2f(uq.x); q[v][1] = b2f(uq.y); q[v][2] = b2f(uq.z); q[v][3] = b2f(uq.w);
        k[v][0] = b2f(uk.x); k[v][1] = b2f(uk.y); k[v][2] = b2f(uk.z); k[v][3] = b2f(uk.w);
        vv[v][0] = b2f(uv.x); vv[v][1] = b2f(uv.y); vv[v][2] = b2f(uv.z); vv[v][3] = b2f(uv.w);
    }
    float s[4][4];
#pragma unroll
    for (int v = 0; v < 4; ++v)
#pragma unroll
        for (int wv = 0; wv < 4; ++wv) {
            float acc = 0.f;
#pragma unroll
            for (int j = 0; j < 4; ++j) acc += q[v][j] * k[wv][j];
            s[v][wv] = acc;
        }
#pragma unroll
    for (int v = 0; v < 4; ++v)
#pragma unroll
        for (int wv = 0; wv < 4; ++wv) {
            float x = s[v][wv];
#pragma unroll
            for (int off = 32; off; off >>= 1) x += __shfl_down(x, off);
            if (lane == 0) red[wid * 16 + v * 4 + wv] = x;
        }
    __syncthreads();
    if (t < 16) {
        float tot = (red[t] + red[16 + t] + red[32 + t] + red[48 + t]) * 0.03125f; // /sqrt(1024)
        red[t] = tot;
    }
    __syncthreads();
    if (t < 4) {
        float s0 = red[t * 4], s1 = red[t * 4 + 1], s2 = red[t * 4 + 2], s3 = red[t * 4 + 3];
        float mx = fmaxf(fmaxf(s0, s1), fmaxf(s2, s3));
        float e0 = __expf(s0 - mx), e1 = __expf(s1 - mx), e2 = __expf(s2 - mx), e3 = __expf(s3 - mx);
        float inv = 1.f / (e0 + e1 + e2 + e3);
        attn_s[t * 4 + 0] = e0 * inv; attn_s[t * 4 + 1] = e1 * inv;
        attn_s[t * 4 + 2] = e2 * inv; attn_s[t * 4 + 3] = e3 * inv;
    }
    __syncthreads();
    float a_[4][4];
#pragma unroll
    for (int v = 0; v < 4; ++v)
#pragma unroll
        for (int wv = 0; wv < 4; ++wv) a_[v][wv] = attn_s[v * 4 + wv];

    float x[4][4];
    float sum = 0.f, sumsq = 0.f;
#pragma unroll
    for (int v = 0; v < 4; ++v) {
        ushort4 xr = *(const ushort4*)(xb + (size_t)(b * 4 + v) * 1024 + h0);
        float xv[4] = {b2f(xr.x), b2f(xr.y), b2f(xr.z), b2f(xr.w)};
#pragma unroll
        for (int j = 0; j < 4; ++j) {
            float val = a_[v][0] * vv[0][j] + a_[v][1] * vv[1][j] +
                        a_[v][2] * vv[2][j] + a_[v][3] * vv[3][j] + xv[j];
            x[v][j] = val;
            sum += val; sumsq += val * val;
        }
    }
#pragma unroll
    for (int off = 32; off; off >>= 1) {
        sum += __shfl_down(sum, off);
        sumsq += __shfl_down(sumsq, off);
    }
    __syncthreads();
    if (lane == 0) { red[wid] = sum; red[8 + wid] = sumsq; }
    __syncthreads();
    if (t == 0) {
        float sm = red[0] + red[1] + red[2] + red[3];
        float sq = red[8] + red[9] + red[10] + red[11];
        float mean = sm * (1.f / 4096.f);
        float var = sq * (1.f / 4096.f) - mean * mean;
        mv2[0] = mean; mv2[1] = rsqrtf(var + 1e-5f);
    }
    __syncthreads();
    float mean = mv2[0], rstd = mv2[1];
#pragma unroll
    for (int v = 0; v < 4; ++v) {
        ushort4 o;
        o.x = f2b((x[v][0] - mean) * rstd);
        o.y = f2b((x[v][1] - mean) * rstd);
        o.z = f2b((x[v][2] - mean) * rstd);
        o.w = f2b((x[v][3] - mean) * rstd);
        *(ushort4*)(xln + (size_t)(b * 4 + v) * 1024 + h0) = o;
    }
}

// ---------------- classifier: partial[split] = h(8192x4096) @ Wft(16x4096)^T over K/4 ----------------
__global__ __launch_bounds__(256) void final_mfma(
    const unsigned short* __restrict__ A, const unsigned short* __restrict__ Bt,
    float* __restrict__ part) {
    __shared__ __align__(16) short ldsA[128 * 64];
    __shared__ __align__(16) short ldsB[16 * 64];
    const int t = threadIdx.x;
    const int w = t >> 6, lane = t & 63;
    const int row0 = blockIdx.x * 128;
    const int split = blockIdx.y;
    const int kbase = split * 1024;
    const int rl = lane >> 3;
    const int sl = (lane & 7) ^ rl;

    const unsigned short* gA[4];
#pragma unroll
    for (int i = 0; i < 4; ++i) {
        int r = (w * 4 + i) * 8 + rl;
        gA[i] = A + (size_t)(row0 + r) * 4096 + kbase + sl * 8;
    }
    const unsigned short* gB = Bt;
    if (w < 2) gB = Bt + (size_t)(w * 8 + rl) * 4096 + kbase + sl * 8;

    f32x4_t acc[2] = {};
    const int hi = lane >> 4;
    const int l7 = lane & 7;

    for (int kt = 0; kt < 1024; kt += 64) {
#pragma unroll
        for (int i = 0; i < 4; ++i) gload16((const void*)(gA[i] + kt), ldsA + (w * 4 + i) * 512);
        if (w < 2) gload16((const void*)(gB + kt), ldsB + w * 512);
        __syncthreads();
#pragma unroll
        for (int kk = 0; kk < 2; ++kk) {
            const int s = ((kk * 4 + hi) ^ l7) * 8;
            bf16x8_t bfr = *(const bf16x8_t*)&ldsB[(lane & 15) * 64 + s];
#pragma unroll
            for (int m = 0; m < 2; ++m) {
                bf16x8_t af = *(const bf16x8_t*)&ldsA[(w * 32 + m * 16 + (lane & 15)) * 64 + s];
                acc[m] = __builtin_amdgcn_mfma_f32_16x16x32_bf16(af, bfr, acc[m], 0, 0, 0);
            }
        }
        __syncthreads();
    }
    const int col = lane & 15;
    if (col < 10) {
#pragma unroll
        for (int m = 0; m < 2; ++m)
#pragma unroll
            for (int j = 0; j < 4; ++j) {
                int row = row0 + w * 32 + m * 16 + ((lane >> 4) << 2) + j;
                part[(size_t)split * 81920 + (size_t)row * 10 + col] = acc[m][j];
            }
    }
}

__global__ __launch_bounds__(256) void reduce_out(const float* __restrict__ part,
                                                  const float* __restrict__ bias,
                                                  float* __restrict__ out) {
    int i = blockIdx.x * 256 + threadIdx.x; // 81920 total
    if (i < 81920) {
        int c = i - (i / 10) * 10;
        out[i] = part[i] + part[81920 + i] + part[2 * 81920 + i] + part[3 * 81920 + i] + bias[c];
    }
}

extern "C" void kernel_launch(void* const* d_in, const int* in_sizes, int n_in,
                              void* d_out, int out_size, void* d_ws, size_t ws_size,
                              hipStream_t stream) {
    const float* xt = (const float*)d_in[0];
    const float* Wq = (const float*)d_in[1];
    const float* bq = (const float*)d_in[2];
    const float* Wk = (const float*)d_in[3];
    const float* bk = (const float*)d_in[4];
    const float* Wv = (const float*)d_in[5];
    const float* bv = (const float*)d_in[6];
    const float* W1 = (const float*)d_in[7];
    const float* b1 = (const float*)d_in[8];
    const float* Wf = (const float*)d_in[9];
    const float* bff = (const float*)d_in[10];
    float* out = (float*)d_out;
    char* ws = (char*)d_ws;

    unsigned short* xb  = (unsigned short*)(ws + 0);          // 64 MiB (reused as xln)
    unsigned short* wt3 = (unsigned short*)(ws + 67108864);   // 6 MiB  (Wq|Wk|Wv transposed)
    unsigned short* w1t = (unsigned short*)(ws + 73400320);   // 2 MiB
    unsigned short* wft = (unsigned short*)(ws + 75497472);   // 128 KiB
    float* part         = (float*)(ws + 75628544);            // 1.25 MiB
    unsigned short* qkv = (unsigned short*)(ws + 77070336);   // 192 MiB (reused as h)
    unsigned short* xln = xb;
    unsigned short* hbuf = qkv;

    cast_bf16<<<2048, 256, 0, stream>>>(xt, xb, 32768 * 1024);
    dim3 tb(32, 8), tg(32, 32);
    transpose_cast<<<tg, tb, 0, stream>>>(Wq, wt3);
    transpose_cast<<<tg, tb, 0, stream>>>(Wk, wt3 + 1024 * 1024);
    transpose_cast<<<tg, tb, 0, stream>>>(Wv, wt3 + 2 * 1024 * 1024);
    transpose_cast<<<tg, tb, 0, stream>>>(W1, w1t);
    wft_prep<<<256, 256, 0, stream>>>(Wf, wft);

    // qkv = xb @ [Wq|Wk|Wv]^T : M=32768, N=3072, K=1024 -> grid 12*128 = 1536 (%8==0)
    gemm256<0, 1024><<<1536, 512, 0, stream>>>(xb, wt3, qkv, bq, bk, bv, 3072);
    // attention + residual + LN
    attn_ln<<<8192, 256, 0, stream>>>(qkv, xb, xln);
    // h = relu(xln @ W1^T + b1) : N=1024 -> grid 4*128 = 512 (%8==0)
    gemm256<1, 1024><<<512, 512, 0, stream>>>(xln, w1t, hbuf, b1, b1, b1, 1024);
    // classifier split-K
    final_mfma<<<dim3(64, 4), 256, 0, stream>>>(hbuf, wft, part);
    reduce_out<<<320, 256, 0, stream>>>(part, bff, out);
}